// Round 2
// baseline (1046.824 us; speedup 1.0000x reference)
//
#include <hip/hip_runtime.h>
#include <math.h>

#define B_ 8
#define S_ 4
#define T_ 2048
#define L_ 2
#define NH_ 32
#define NKV_ 8
#define HD_ 128
#define DIM_ 4096
#define M_ 32            // B_*S_ token rows
#define QKVC_ 6144       // 4096 q + 1024 k + 1024 v columns
#define QK_SCALE 0.08838834764831845f   // 1/sqrt(128)

typedef float f32x4 __attribute__((ext_vector_type(4)));

// ---------------------------------------------------------------------------
// zero the atomic-accumulation buffers (ws qkv region + d_out)
// ---------------------------------------------------------------------------
__global__ __launch_bounds__(256) void zero2_k(float* __restrict__ a, int na,
                                               float* __restrict__ b, int nb) {
  int i = blockIdx.x * 256 + threadIdx.x;
  int st = gridDim.x * 256;
  for (int j = i; j < na; j += st) a[j] = 0.f;
  for (int j = i; j < nb; j += st) b[j] = 0.f;
}

// ---------------------------------------------------------------------------
// Small-M GEMM: out[32][outw] += X[32][4096] @ W^T   (W row-major [rows][4096])
// Column-block selects among up to 3 weight matrices (wq|wk|wv packed outputs).
// K split 8 ways across blockIdx.y; partials land via atomicAdd.
// LDS double-buffered via register staging so weight streaming overlaps FMAs.
// ---------------------------------------------------------------------------
#define GCOLS 64
#define GKT 128
#define GKCHUNK 512   // 4096 / 8-way k-split

__global__ __launch_bounds__(256) void gemm32_k(
    const float* __restrict__ X,
    const float* __restrict__ W0, const float* __restrict__ W1,
    const float* __restrict__ W2, int n0, int n1,
    float* __restrict__ out, int outw)
{
  __shared__ __align__(16) float xs[2][M_][GKT + 4];      // 33.8 KB
  __shared__ __align__(16) float ws_[2][GCOLS][GKT + 4];  // 67.6 KB
  const int tid = threadIdx.x;
  const int colbase = blockIdx.x * GCOLS;
  const int k0base = blockIdx.y * GKCHUNK;
  const float* W; int wr0;
  if (colbase < n0)           { W = W0; wr0 = colbase; }
  else if (colbase < n0 + n1) { W = W1; wr0 = colbase - n0; }
  else                        { W = W2; wr0 = colbase - n0 - n1; }

  const int mg = tid >> 5;   // 0..7  -> rows 4*mg+i
  const int cg = tid & 31;   // cols cg + 32*j

  f32x4 sx[4], sw[8];
  auto load_stage = [&](int kt) {
    const int k0 = k0base + kt;
#pragma unroll
    for (int i = 0; i < 4; ++i) {
      int idx = tid + 256 * i, m = idx >> 5, k4 = idx & 31;
      sx[i] = *(const f32x4*)(X + (size_t)m * DIM_ + k0 + k4 * 4);
    }
#pragma unroll
    for (int i = 0; i < 8; ++i) {
      int idx = tid + 256 * i, c = idx >> 5, k4 = idx & 31;
      sw[i] = *(const f32x4*)(W + (size_t)(wr0 + c) * DIM_ + k0 + k4 * 4);
    }
  };
  auto store_stage = [&](int buf) {
#pragma unroll
    for (int i = 0; i < 4; ++i) {
      int idx = tid + 256 * i, m = idx >> 5, k4 = idx & 31;
      *(f32x4*)&xs[buf][m][k4 * 4] = sx[i];
    }
#pragma unroll
    for (int i = 0; i < 8; ++i) {
      int idx = tid + 256 * i, c = idx >> 5, k4 = idx & 31;
      *(f32x4*)&ws_[buf][c][k4 * 4] = sw[i];
    }
  };

  float acc[4][2];
#pragma unroll
  for (int i = 0; i < 4; ++i) { acc[i][0] = 0.f; acc[i][1] = 0.f; }

  load_stage(0);
  store_stage(0);
  __syncthreads();
  const int NT = GKCHUNK / GKT;   // 4
  for (int ti = 0; ti < NT; ++ti) {
    if (ti + 1 < NT) load_stage((ti + 1) * GKT);   // prefetch next tile -> regs
    const int buf = ti & 1;
#pragma unroll 4
    for (int k4 = 0; k4 < GKT / 4; ++k4) {
      f32x4 xv[4], wv[2];
#pragma unroll
      for (int i = 0; i < 4; ++i) xv[i] = *(const f32x4*)&xs[buf][4 * mg + i][k4 * 4];
#pragma unroll
      for (int j = 0; j < 2; ++j) wv[j] = *(const f32x4*)&ws_[buf][cg + 32 * j][k4 * 4];
#pragma unroll
      for (int i = 0; i < 4; ++i)
#pragma unroll
        for (int j = 0; j < 2; ++j)
          acc[i][j] += xv[i].x * wv[j].x + xv[i].y * wv[j].y +
                       xv[i].z * wv[j].z + xv[i].w * wv[j].w;
    }
    if (ti + 1 < NT) store_stage((ti + 1) & 1);    // other buffer: no race with readers
    __syncthreads();
  }
#pragma unroll
  for (int i = 0; i < 4; ++i)
#pragma unroll
    for (int j = 0; j < 2; ++j)
      atomicAdd(out + (size_t)(4 * mg + i) * outw + colbase + cg + 32 * j, acc[i][j]);
}

// ---------------------------------------------------------------------------
// RoPE on q,k + write repeated k/v into cache_k/cache_v (layer li, row sp+s).
// grid = 32 blocks, one per (b,s) token row.
// ---------------------------------------------------------------------------
__global__ __launch_bounds__(256) void rope_cache_k(
    const float* __restrict__ qkv, const float* __restrict__ angles,
    const int* __restrict__ start_pos, const int* __restrict__ layer_idx,
    float* __restrict__ q_rope, float* __restrict__ cache_k,
    float* __restrict__ cache_v)
{
  const int bs = blockIdx.x;              // 0..31
  const int b = bs >> 2, s = bs & 3;
  const int tid = threadIdx.x;
  const int li = *layer_idx;
  const int sp = start_pos[b];
  const float* qrow = qkv + (size_t)bs * QKVC_;
  const float* krow = qrow + DIM_;
  const float* vrow = qrow + DIM_ + NKV_ * HD_;
  const float* ang = angles + bs * (HD_ / 2);
  const size_t cbase = ((size_t)(b * T_ + sp + s) * L_ + li) * (size_t)(NH_ * HD_);

  // q rope: 2048 pairs
  for (int p = tid; p < 2048; p += 256) {
    int hh = p >> 6, j = p & 63;
    float a = ang[j], c = cosf(a), sn = sinf(a);
    int col = hh * HD_ + 2 * j;
    float xr = qrow[col], xi = qrow[col + 1];
    float2 o = { xr * c - xi * sn, xr * sn + xi * c };
    *(float2*)(q_rope + (size_t)bs * DIM_ + col) = o;
  }
  // k rope + 4-rep cache write: 512 pairs
  for (int p = tid; p < 512; p += 256) {
    int hh = p >> 6, j = p & 63;
    float a = ang[j], c = cosf(a), sn = sinf(a);
    int col = hh * HD_ + 2 * j;
    float xr = krow[col], xi = krow[col + 1];
    float2 o = { xr * c - xi * sn, xr * sn + xi * c };
#pragma unroll
    for (int r = 0; r < 4; ++r)
      *(float2*)(cache_k + cbase + (size_t)(hh * 4 + r) * HD_ + 2 * j) = o;
  }
  // v copy + 4-rep: 512 float2
  for (int p = tid; p < 512; p += 256) {
    int hh = p >> 6, d = (p & 63) * 2;
    float2 v = *(const float2*)(vrow + hh * HD_ + d);
#pragma unroll
    for (int r = 0; r < 4; ++r)
      *(float2*)(cache_v + cbase + (size_t)(hh * 4 + r) * HD_ + d) = v;
  }
}

// ---------------------------------------------------------------------------
// Attention: one block per (b,h). K/V tiles (64 x 128, stride-pad 132) stream
// through double-buffered LDS (nontemporal global loads: zero-reuse stream,
// keep weights/L3 clean for the wo GEMM); all 4x2048 scores live in LDS;
// wave-per-row softmax; PV with float2 accumulators.
// ---------------------------------------------------------------------------
__global__ __launch_bounds__(256) void attn_k(
    const float* __restrict__ q_rope, const float* __restrict__ cache_k,
    const float* __restrict__ cache_v, const float* __restrict__ mask,
    const int* __restrict__ layer_idx, float* __restrict__ attn_out)
{
  __shared__ __align__(16) float qs[S_][132];        // 2.1 KB
  __shared__ __align__(16) float kv[2][64][132];     // 67.6 KB
  __shared__ __align__(16) float sc[S_][T_ + 4];     // 32.8 KB
  __shared__ float rsum[S_];
  const int tid = threadIdx.x;
  const int b = blockIdx.x >> 5, h = blockIdx.x & 31;
  const int li = *layer_idx;

  { // q load (pre-scaled by 1/sqrt(HD))
    int flat = tid * 2, s = flat >> 7, d = flat & 127;
    float2 v = *(const float2*)(q_rope + (size_t)(b * S_ + s) * DIM_ + h * HD_ + d);
    qs[s][d] = v.x * QK_SCALE; qs[s][d + 1] = v.y * QK_SCALE;
  }

  const size_t rstride = (size_t)L_ * NH_ * HD_;   // 8192 floats between t rows
  const size_t lbase = ((size_t)b * T_ * L_ + li) * (size_t)(NH_ * HD_) + (size_t)h * HD_;
  const float* kbase = cache_k + lbase;
  const float* vbase = cache_v + lbase;

  f32x4 stg[8];
  auto load_tile = [&](const float* basep, int t0) {
#pragma unroll
    for (int i = 0; i < 8; ++i) {
      int idx = tid + 256 * i, r = idx >> 5, k4 = idx & 31;
      stg[i] = __builtin_nontemporal_load(
          (const f32x4*)(basep + (size_t)(t0 + r) * rstride + k4 * 4));
    }
  };
  auto store_tile = [&](int buf) {
#pragma unroll
    for (int i = 0; i < 8; ++i) {
      int idx = tid + 256 * i, r = idx >> 5, k4 = idx & 31;
      *(f32x4*)&kv[buf][r][k4 * 4] = stg[i];
    }
  };

  // ---- scores: each thread owns one (m, row) per tile
  load_tile(kbase, 0);
  store_tile(0);
  __syncthreads();
  const int m = tid & 3, rr = tid >> 2;
  for (int ti = 0; ti < 32; ++ti) {
    if (ti + 1 < 32) load_tile(kbase, (ti + 1) * 64);
    float a = 0.f;
#pragma unroll 8
    for (int d4 = 0; d4 < 32; ++d4) {
      f32x4 qv = *(const f32x4*)&qs[m][d4 * 4];
      f32x4 kk = *(const f32x4*)&kv[ti & 1][rr][d4 * 4];
      a += qv.x * kk.x + qv.y * kk.y + qv.z * kk.z + qv.w * kk.w;
    }
    int t = ti * 64 + rr;
    sc[m][t] = a + mask[m * T_ + t];
    if (ti + 1 < 32) store_tile((ti + 1) & 1);
    __syncthreads();
  }

  // ---- softmax: wave w handles row w (values kept unnormalized; 1/sum saved)
  const int w = tid >> 6, lane = tid & 63;
  {
    float mx = -1e30f;
    for (int i = lane; i < T_; i += 64) mx = fmaxf(mx, sc[w][i]);
#pragma unroll
    for (int o = 32; o; o >>= 1) mx = fmaxf(mx, __shfl_xor(mx, o, 64));
    float sum = 0.f;
    for (int i = lane; i < T_; i += 64) {
      float e = expf(sc[w][i] - mx);
      sc[w][i] = e;
      sum += e;
    }
#pragma unroll
    for (int o = 32; o; o >>= 1) sum += __shfl_xor(sum, o, 64);
    if (lane == 0) rsum[w] = 1.f / sum;
  }
  __syncthreads();

  // ---- PV: wave w owns output row w; lane owns d0=2*lane, 2*lane+1
  load_tile(vbase, 0);
  store_tile(0);
  __syncthreads();
  const int d0 = lane * 2;
  float ax = 0.f, ay = 0.f;
  for (int ti = 0; ti < 32; ++ti) {
    if (ti + 1 < 32) load_tile(vbase, (ti + 1) * 64);
    const int t0 = ti * 64, buf = ti & 1;
#pragma unroll 4
    for (int q4 = 0; q4 < 16; ++q4) {
      f32x4 p4 = *(const f32x4*)&sc[w][t0 + q4 * 4];
#pragma unroll
      for (int u = 0; u < 4; ++u) {
        float p = p4[u];
        float2 vv = *(const float2*)&kv[buf][q4 * 4 + u][d0];
        ax += p * vv.x; ay += p * vv.y;
      }
    }
    if (ti + 1 < 32) store_tile((ti + 1) & 1);
    __syncthreads();
  }
  float rs = rsum[w];
  float2 o2 = { ax * rs, ay * rs };
  *(float2*)(attn_out + (size_t)(b * S_ + w) * DIM_ + h * HD_ + d0) = o2;
}

// ---------------------------------------------------------------------------
extern "C" void kernel_launch(void* const* d_in, const int* in_sizes, int n_in,
                              void* d_out, int out_size, void* d_ws, size_t ws_size,
                              hipStream_t stream) {
  const float* x         = (const float*)d_in[0];
  const int*   start_pos = (const int*)d_in[1];
  const float* angles    = (const float*)d_in[2];
  float*       cache_k   = (float*)d_in[3];
  float*       cache_v   = (float*)d_in[4];
  const float* mask      = (const float*)d_in[5];
  const float* wq        = (const float*)d_in[6];
  const float* wk        = (const float*)d_in[7];
  const float* wv        = (const float*)d_in[8];
  const float* wo        = (const float*)d_in[9];
  const int*   layer_idx = (const int*)d_in[10];
  float* out = (float*)d_out;

  float* qkv    = (float*)d_ws;                    // [32][6144] accum (needs zero)
  float* q_rope = qkv + (size_t)M_ * QKVC_;        // [32][4096]
  float* attn_o = q_rope + (size_t)M_ * DIM_;      // [32][4096]

  zero2_k<<<320, 256, 0, stream>>>(qkv, M_ * QKVC_, out, M_ * DIM_);
  // QKV projections: one launch, column-block selects wq/wk/wv
  gemm32_k<<<dim3(QKVC_ / GCOLS, 8), 256, 0, stream>>>(
      x, wq, wk, wv, NH_ * HD_, NKV_ * HD_, qkv, QKVC_);
  rope_cache_k<<<32, 256, 0, stream>>>(qkv, angles, start_pos, layer_idx,
                                       q_rope, cache_k, cache_v);
  attn_k<<<B_ * NH_, 256, 0, stream>>>(q_rope, cache_k, cache_v, mask,
                                       layer_idx, attn_o);
  // output projection
  gemm32_k<<<dim3(DIM_ / GCOLS, 8), 256, 0, stream>>>(
      attn_o, wo, wo, wo, DIM_, 0, out, DIM_);
}